// Round 1
// baseline (348.998 us; speedup 1.0000x reference)
//
#include <hip/hip_runtime.h>

#define SEQ 4096
#define DM  1024
#define NH  16
#define HD  64

typedef __attribute__((ext_vector_type(8))) short bf16x8;
typedef __attribute__((ext_vector_type(4))) float f32x4;

__device__ __forceinline__ unsigned short f2bf(float f){
  unsigned int u = __float_as_uint(f);
  u += 0x7fffu + ((u >> 16) & 1u);
  return (unsigned short)(u >> 16);
}

__device__ __forceinline__ void gload_lds16(const void* g, void* l){
  __builtin_amdgcn_global_load_lds(
      (const __attribute__((address_space(1))) unsigned int*)g,
      (__attribute__((address_space(3))) unsigned int*)l,
      16, 0, 0);
}

__global__ __launch_bounds__(256) void f2bf_kernel(const float* __restrict__ src,
                                                   unsigned short* __restrict__ dst, int n4){
  int i = blockIdx.x * 256 + threadIdx.x;
  int stride = gridDim.x * 256;
  for (; i < n4; i += stride){
    float4 v = ((const float4*)src)[i];
    ushort4 o; o.x = f2bf(v.x); o.y = f2bf(v.y); o.z = f2bf(v.z); o.w = f2bf(v.w);
    ((ushort4*)dst)[i] = o;
  }
}

// cos/sin table: tab[s*32 + i] = {cos(s*theta^(-2i/64)), sin(...)}
__global__ __launch_bounds__(256) void rope_tab_kernel(float2* __restrict__ tab){
  int i = blockIdx.x * 256 + threadIdx.x;   // 0 .. SEQ*32-1
  int s = i >> 5, f = i & 31;
  double inv = pow(10000.0, -2.0 * (double)f / 64.0);
  double a = (double)s * inv;
  tab[i] = make_float2((float)cos(a), (float)sin(a));
}

// C[row,col] = sum_k A[row,k] * B[col,k]   (A: MxK row-major, B: NxK row-major)
// MODE 0: RoPE epilogue, bf16 store to Cout[row*N+col]
// MODE 1: bf16 transposed store Cout[col*M+row]  (for V)
// MODE 2: f32 store Cout[row*N+col]              (final output)
template<int MODE>
__global__ __launch_bounds__(256) void gemm_bt(const unsigned short* __restrict__ A,
                                               const unsigned short* __restrict__ B,
                                               void* __restrict__ Cout,
                                               const float2* __restrict__ rope,
                                               int M, int N, int K)
{
  __shared__ unsigned short At[128 * 32];
  __shared__ unsigned short Bt[128 * 32];
  const int t = threadIdx.x;
  const int lane = t & 63, w = t >> 6;
  const int lg = lane >> 4, lr = lane & 15;
  const int wr = w >> 1, wc = w & 1;
  const int m0 = blockIdx.y * 128, n0 = blockIdx.x * 128;

  f32x4 acc[4][4];
  #pragma unroll
  for (int mi = 0; mi < 4; mi++)
    #pragma unroll
    for (int nj = 0; nj < 4; nj++)
      acc[mi][nj] = (f32x4){0.f, 0.f, 0.f, 0.f};

  for (int k0 = 0; k0 < K; k0 += 32){
    __syncthreads();
    {
      int idx = t;
      gload_lds16(&A[(size_t)(m0 + (idx >> 2)) * K + k0 + (idx & 3) * 8], &At[idx * 8]);
      gload_lds16(&B[(size_t)(n0 + (idx >> 2)) * K + k0 + (idx & 3) * 8], &Bt[idx * 8]);
      idx = t + 256;
      gload_lds16(&A[(size_t)(m0 + (idx >> 2)) * K + k0 + (idx & 3) * 8], &At[idx * 8]);
      gload_lds16(&B[(size_t)(n0 + (idx >> 2)) * K + k0 + (idx & 3) * 8], &Bt[idx * 8]);
    }
    __syncthreads();
    bf16x8 af[4], bfr[4];
    #pragma unroll
    for (int mi = 0; mi < 4; mi++)
      af[mi] = *(const bf16x8*)&At[(wr * 64 + mi * 16 + lr) * 32 + lg * 8];
    #pragma unroll
    for (int nj = 0; nj < 4; nj++)
      bfr[nj] = *(const bf16x8*)&Bt[(wc * 64 + nj * 16 + lr) * 32 + lg * 8];
    #pragma unroll
    for (int mi = 0; mi < 4; mi++)
      #pragma unroll
      for (int nj = 0; nj < 4; nj++)
        acc[mi][nj] = __builtin_amdgcn_mfma_f32_16x16x32_bf16(af[mi], bfr[nj], acc[mi][nj], 0, 0, 0);
  }

  #pragma unroll
  for (int mi = 0; mi < 4; mi++){
    #pragma unroll
    for (int nj = 0; nj < 4; nj++){
      f32x4 v = acc[mi][nj];
      int col  = n0 + wc * 64 + nj * 16 + lr;
      int row0 = m0 + wr * 64 + mi * 16 + lg * 4;
      if (MODE == 0){
        #pragma unroll
        for (int j = 0; j < 4; j++){
          float val = v[j];
          float oth = __shfl_xor(val, 1);
          int row = row0 + j;
          int i = (col & 63) >> 1;
          float2 cs = rope[row * 32 + i];
          float res = ((col & 1) == 0) ? (val * cs.x - oth * cs.y)
                                       : (oth * cs.y + val * cs.x);
          ((unsigned short*)Cout)[(size_t)row * N + col] = f2bf(res);
        }
      } else if (MODE == 1){
        ushort4 pk; pk.x = f2bf(v[0]); pk.y = f2bf(v[1]); pk.z = f2bf(v[2]); pk.w = f2bf(v[3]);
        *(ushort4*)&((unsigned short*)Cout)[(size_t)col * M + row0] = pk;
      } else {
        #pragma unroll
        for (int j = 0; j < 4; j++)
          ((float*)Cout)[(size_t)(row0 + j) * N + col] = v[j];
      }
    }
  }
}

// Flash attention: grid (SEQ/64, NH), 256 threads (4 waves x 16 q-rows).
// Qb/Kb: [SEQ][DM] bf16 (post-RoPE). Vt: [DM][SEQ] bf16 (per-head transposed).
// AO: [SEQ][DM] bf16 out.
__global__ __launch_bounds__(256) void attn_kernel(const unsigned short* __restrict__ Qb,
                                                   const unsigned short* __restrict__ Kb,
                                                   const unsigned short* __restrict__ Vt,
                                                   unsigned short* __restrict__ AO)
{
  __shared__ unsigned short Kt[64 * 64];   // (key,d) chunk-swizzled
  __shared__ unsigned short Vts[64 * 64];  // (dh,key) chunk-swizzled
  __shared__ unsigned short Pl[4][16 * 64];

  const int h = blockIdx.y;
  const int q0 = blockIdx.x * 64;
  const int t = threadIdx.x;
  const int w = t >> 6, lane = t & 63;
  const int lg = lane >> 4, lr = lane & 15;

  // Q fragments in registers (A layout: row = lr, k = 8*lg + j)
  const int qrow = q0 + w * 16 + lr;
  bf16x8 qf[2];
  qf[0] = *(const bf16x8*)&Qb[(size_t)qrow * DM + h * 64 + 0  + lg * 8];
  qf[1] = *(const bf16x8*)&Qb[(size_t)qrow * DM + h * 64 + 32 + lg * 8];

  f32x4 oacc[4];
  #pragma unroll
  for (int n = 0; n < 4; n++) oacc[n] = (f32x4){0.f, 0.f, 0.f, 0.f};
  float mrun[4], lrun[4];
  #pragma unroll
  for (int j = 0; j < 4; j++){ mrun[j] = -INFINITY; lrun[j] = 0.f; }

  unsigned short* Pm = &Pl[w][0];
  const int ntiles = q0 / 64 + 1;

  for (int tt = 0; tt < ntiles; ++tt){
    const int k0 = tt * 64;
    // stage K (key rows, 128B = 8 chunks, source-side XOR swizzle) and V^T
    #pragma unroll
    for (int r = 0; r < 2; r++){
      int idx = r * 256 + t; int row = idx >> 3; int ch = idx & 7; int cs = ch ^ (row & 7);
      gload_lds16(&Kb[(size_t)(k0 + row) * DM + h * 64 + cs * 8], &Kt[idx * 8]);
    }
    #pragma unroll
    for (int r = 0; r < 2; r++){
      int idx = r * 256 + t; int row = idx >> 3; int ch = idx & 7; int cs = ch ^ (row & 7);
      gload_lds16(&Vt[(size_t)(h * 64 + row) * SEQ + k0 + cs * 8], &Vts[idx * 8]);
    }
    __syncthreads();

    // S = Q K^T  (16 q-rows x 64 keys per wave)
    f32x4 sa[4];
    #pragma unroll
    for (int nt = 0; nt < 4; nt++){
      sa[nt] = (f32x4){0.f, 0.f, 0.f, 0.f};
      #pragma unroll
      for (int kk = 0; kk < 2; kk++){
        int key = nt * 16 + lr;
        int slot = (kk * 4 + lg) ^ (key & 7);
        bf16x8 kf = *(const bf16x8*)((const char*)Kt + key * 128 + slot * 16);
        sa[nt] = __builtin_amdgcn_mfma_f32_16x16x32_bf16(qf[kk], kf, sa[nt], 0, 0, 0);
      }
    }

    const bool diag = (k0 == q0);
    // online softmax per row (row = lg*4 + j across the 16 lanes of the group)
    #pragma unroll
    for (int j = 0; j < 4; j++){
      const int qr = q0 + w * 16 + lg * 4 + j;
      float mx = -INFINITY;
      #pragma unroll
      for (int nt = 0; nt < 4; nt++){
        float s = sa[nt][j] * 0.125f;
        int key = k0 + nt * 16 + lr;
        if (diag && key > qr) s = -INFINITY;
        sa[nt][j] = s;
        mx = fmaxf(mx, s);
      }
      #pragma unroll
      for (int d = 1; d < 16; d <<= 1) mx = fmaxf(mx, __shfl_xor(mx, d));
      float mnew = fmaxf(mrun[j], mx);
      float alpha = __expf(mrun[j] - mnew);
      float psum = 0.f;
      #pragma unroll
      for (int nt = 0; nt < 4; nt++){
        float p = __expf(sa[nt][j] - mnew);
        sa[nt][j] = p;
        psum += p;
      }
      #pragma unroll
      for (int d = 1; d < 16; d <<= 1) psum += __shfl_xor(psum, d);
      lrun[j] = lrun[j] * alpha + psum;
      mrun[j] = mnew;
      #pragma unroll
      for (int n = 0; n < 4; n++) oacc[n][j] *= alpha;
      // store P (row rq, key) swizzled for A-layout readback
      const int rq = lg * 4 + j;
      #pragma unroll
      for (int nt = 0; nt < 4; nt++){
        int key = nt * 16 + lr;
        int slot = (key >> 3) ^ (rq & 7);
        *(unsigned short*)((char*)Pm + rq * 128 + slot * 16 + (key & 7) * 2) = f2bf(sa[nt][j]);
      }
    }
    asm volatile("s_waitcnt lgkmcnt(0)" ::: "memory");

    // O += P V  (A = P[16x32 key-slice], B = V[key][dh] from Vts[dh][key])
    #pragma unroll
    for (int kk = 0; kk < 2; kk++){
      int pslot = (kk * 4 + lg) ^ (lr & 7);
      bf16x8 pf = *(const bf16x8*)((const char*)Pm + lr * 128 + pslot * 16);
      #pragma unroll
      for (int nd = 0; nd < 4; nd++){
        int dh = nd * 16 + lr;
        int vslot = (kk * 4 + lg) ^ (dh & 7);
        bf16x8 vf = *(const bf16x8*)((const char*)Vts + dh * 128 + vslot * 16);
        oacc[nd] = __builtin_amdgcn_mfma_f32_16x16x32_bf16(pf, vf, oacc[nd], 0, 0, 0);
      }
    }
    __syncthreads();
  }

  // epilogue: O /= l, store bf16
  #pragma unroll
  for (int nd = 0; nd < 4; nd++){
    #pragma unroll
    for (int j = 0; j < 4; j++){
      int qr = q0 + w * 16 + lg * 4 + j;
      float o = oacc[nd][j] / lrun[j];
      AO[(size_t)qr * DM + h * 64 + nd * 16 + lr] = f2bf(o);
    }
  }
}

extern "C" void kernel_launch(void* const* d_in, const int* in_sizes, int n_in,
                              void* d_out, int out_size, void* d_ws, size_t ws_size,
                              hipStream_t stream)
{
  const float* x  = (const float*)d_in[0];
  const float* Wq = (const float*)d_in[1];
  const float* Wk = (const float*)d_in[2];
  const float* Wv = (const float*)d_in[3];
  const float* Wo = (const float*)d_in[4];

  char* ws = (char*)d_ws;
  unsigned short* xb  = (unsigned short*)ws; ws += (size_t)SEQ * DM * 2;
  unsigned short* wqb = (unsigned short*)ws; ws += (size_t)DM * DM * 2;
  unsigned short* wkb = (unsigned short*)ws; ws += (size_t)DM * DM * 2;
  unsigned short* wvb = (unsigned short*)ws; ws += (size_t)DM * DM * 2;
  unsigned short* wob = (unsigned short*)ws; ws += (size_t)DM * DM * 2;
  unsigned short* Qb  = (unsigned short*)ws; ws += (size_t)SEQ * DM * 2;
  unsigned short* Kb  = (unsigned short*)ws; ws += (size_t)SEQ * DM * 2;
  unsigned short* Vt  = (unsigned short*)ws; ws += (size_t)DM * SEQ * 2;
  unsigned short* AO  = (unsigned short*)ws; ws += (size_t)SEQ * DM * 2;
  float2* ropetab     = (float2*)ws;         ws += (size_t)SEQ * 32 * sizeof(float2);

  f2bf_kernel<<<1024, 256, 0, stream>>>(x,  xb,  SEQ * DM / 4);
  f2bf_kernel<<<512,  256, 0, stream>>>(Wq, wqb, DM * DM / 4);
  f2bf_kernel<<<512,  256, 0, stream>>>(Wk, wkb, DM * DM / 4);
  f2bf_kernel<<<512,  256, 0, stream>>>(Wv, wvb, DM * DM / 4);
  f2bf_kernel<<<512,  256, 0, stream>>>(Wo, wob, DM * DM / 4);
  rope_tab_kernel<<<SEQ * 32 / 256, 256, 0, stream>>>(ropetab);

  dim3 gg(DM / 128, SEQ / 128);  // (8, 32)
  gemm_bt<0><<<gg, 256, 0, stream>>>(xb, wqb, Qb, ropetab, SEQ, DM, DM);
  gemm_bt<0><<<gg, 256, 0, stream>>>(xb, wkb, Kb, ropetab, SEQ, DM, DM);
  gemm_bt<1><<<gg, 256, 0, stream>>>(xb, wvb, Vt, nullptr, SEQ, DM, DM);

  attn_kernel<<<dim3(SEQ / 64, NH), 256, 0, stream>>>(Qb, Kb, Vt, AO);

  gemm_bt<2><<<gg, 256, 0, stream>>>(AO, wob, (float*)d_out, nullptr, SEQ, DM, DM);
}

// Round 2
// 212.969 us; speedup vs baseline: 1.6387x; 1.6387x over previous
//
#include <hip/hip_runtime.h>
#include <math.h>

#define SEQ 4096
#define DM  1024
#define NH  16

typedef __attribute__((ext_vector_type(8))) short bf16x8;
typedef __attribute__((ext_vector_type(4))) float f32x4;
typedef __attribute__((ext_vector_type(16))) float f32x16;
typedef __attribute__((ext_vector_type(4))) unsigned int u32x4;

// 0.125 (1/sqrt(64)) * log2(e) folded into Q so softmax uses exp2 directly
#define QSCALE 0.18033688011112042f

__device__ __forceinline__ unsigned short f2bf(float f){
  unsigned int u = __float_as_uint(f);
  u += 0x7fffu + ((u >> 16) & 1u);
  return (unsigned short)(u >> 16);
}

__device__ __forceinline__ unsigned int pk2(float lo, float hi){
  return (unsigned int)f2bf(lo) | ((unsigned int)f2bf(hi) << 16);
}

__device__ __forceinline__ void gload_lds16(const void* g, void* l){
  __builtin_amdgcn_global_load_lds(
      (const __attribute__((address_space(1))) unsigned int*)g,
      (__attribute__((address_space(3))) unsigned int*)l,
      16, 0, 0);
}

__global__ __launch_bounds__(256) void f2bf_kernel(const float* __restrict__ src,
                                                   unsigned short* __restrict__ dst, int n4){
  int i = blockIdx.x * 256 + threadIdx.x;
  int stride = gridDim.x * 256;
  for (; i < n4; i += stride){
    float4 v = ((const float4*)src)[i];
    ushort4 o; o.x = f2bf(v.x); o.y = f2bf(v.y); o.z = f2bf(v.z); o.w = f2bf(v.w);
    ((ushort4*)dst)[i] = o;
  }
}

__global__ __launch_bounds__(256) void rope_tab_kernel(float2* __restrict__ tab){
  int i = blockIdx.x * 256 + threadIdx.x;   // 0 .. SEQ*32-1
  int s = i >> 5, f = i & 31;
  double inv = pow(10000.0, -2.0 * (double)f / 64.0);
  double a = (double)s * inv;
  tab[i] = make_float2((float)cos(a), (float)sin(a));
}

// ---------------- fused QKV projection GEMM ----------------
// C[row,col] = sum_k X[row,k] * W[col,k]; grid (24,32): blockIdx.x>>3 selects Q/K/V.
// Q,K: RoPE epilogue (Q additionally scaled by QSCALE), bf16 [SEQ][DM].
// V: transposed bf16 store Vt[col][row] ([DM][SEQ]).
__global__ __launch_bounds__(256) void qkv_gemm(const unsigned short* __restrict__ A,
                                                const unsigned short* __restrict__ Wq,
                                                const unsigned short* __restrict__ Wk,
                                                const unsigned short* __restrict__ Wv,
                                                unsigned short* __restrict__ Qo,
                                                unsigned short* __restrict__ Ko,
                                                unsigned short* __restrict__ Vto,
                                                const float2* __restrict__ rope)
{
  __shared__ unsigned short At[128 * 32];
  __shared__ unsigned short Bt[128 * 32];
  const int sel = blockIdx.x >> 3;
  const unsigned short* B = (sel == 0) ? Wq : (sel == 1) ? Wk : Wv;
  const int K = DM;
  const int t = threadIdx.x;
  const int lane = t & 63, w = t >> 6;
  const int lg = lane >> 4, lr = lane & 15;
  const int wr = w >> 1, wc = w & 1;
  const int m0 = blockIdx.y * 128, n0 = (blockIdx.x & 7) * 128;

  f32x4 acc[4][4];
  #pragma unroll
  for (int mi = 0; mi < 4; mi++)
    #pragma unroll
    for (int nj = 0; nj < 4; nj++)
      acc[mi][nj] = (f32x4){0.f, 0.f, 0.f, 0.f};

  for (int k0 = 0; k0 < K; k0 += 32){
    __syncthreads();
    {
      int idx = t;
      gload_lds16(&A[(size_t)(m0 + (idx >> 2)) * K + k0 + (idx & 3) * 8], &At[idx * 8]);
      gload_lds16(&B[(size_t)(n0 + (idx >> 2)) * K + k0 + (idx & 3) * 8], &Bt[idx * 8]);
      idx = t + 256;
      gload_lds16(&A[(size_t)(m0 + (idx >> 2)) * K + k0 + (idx & 3) * 8], &At[idx * 8]);
      gload_lds16(&B[(size_t)(n0 + (idx >> 2)) * K + k0 + (idx & 3) * 8], &Bt[idx * 8]);
    }
    __syncthreads();
    bf16x8 af[4], bfr[4];
    #pragma unroll
    for (int mi = 0; mi < 4; mi++)
      af[mi] = *(const bf16x8*)&At[(wr * 64 + mi * 16 + lr) * 32 + lg * 8];
    #pragma unroll
    for (int nj = 0; nj < 4; nj++)
      bfr[nj] = *(const bf16x8*)&Bt[(wc * 64 + nj * 16 + lr) * 32 + lg * 8];
    #pragma unroll
    for (int mi = 0; mi < 4; mi++)
      #pragma unroll
      for (int nj = 0; nj < 4; nj++)
        acc[mi][nj] = __builtin_amdgcn_mfma_f32_16x16x32_bf16(af[mi], bfr[nj], acc[mi][nj], 0, 0, 0);
  }

  const float scale = (sel == 0) ? QSCALE : 1.0f;
  unsigned short* Out = (sel == 0) ? Qo : Ko;
  #pragma unroll
  for (int mi = 0; mi < 4; mi++){
    #pragma unroll
    for (int nj = 0; nj < 4; nj++){
      f32x4 v = acc[mi][nj];
      int col  = n0 + wc * 64 + nj * 16 + lr;
      int row0 = m0 + wr * 64 + mi * 16 + lg * 4;
      if (sel < 2){
        #pragma unroll
        for (int j = 0; j < 4; j++){
          float val = v[j];
          float oth = __shfl_xor(val, 1);
          int row = row0 + j;
          int i = (col & 63) >> 1;
          float2 cs = rope[row * 32 + i];
          float res = ((col & 1) == 0) ? (val * cs.x - oth * cs.y)
                                       : (oth * cs.y + val * cs.x);
          Out[(size_t)row * DM + col] = f2bf(res * scale);
        }
      } else {
        ushort4 pkv; pkv.x = f2bf(v[0]); pkv.y = f2bf(v[1]); pkv.z = f2bf(v[2]); pkv.w = f2bf(v[3]);
        *(ushort4*)&Vto[(size_t)col * SEQ + row0] = pkv;
      }
    }
  }
}

// ---------------- output projection GEMM (f32 out) ----------------
__global__ __launch_bounds__(256) void gemm_out(const unsigned short* __restrict__ A,
                                                const unsigned short* __restrict__ B,
                                                float* __restrict__ C)
{
  __shared__ unsigned short At[128 * 32];
  __shared__ unsigned short Bt[128 * 32];
  const int K = DM;
  const int t = threadIdx.x;
  const int lane = t & 63, w = t >> 6;
  const int lg = lane >> 4, lr = lane & 15;
  const int wr = w >> 1, wc = w & 1;
  const int m0 = blockIdx.y * 128, n0 = blockIdx.x * 128;

  f32x4 acc[4][4];
  #pragma unroll
  for (int mi = 0; mi < 4; mi++)
    #pragma unroll
    for (int nj = 0; nj < 4; nj++)
      acc[mi][nj] = (f32x4){0.f, 0.f, 0.f, 0.f};

  for (int k0 = 0; k0 < K; k0 += 32){
    __syncthreads();
    {
      int idx = t;
      gload_lds16(&A[(size_t)(m0 + (idx >> 2)) * K + k0 + (idx & 3) * 8], &At[idx * 8]);
      gload_lds16(&B[(size_t)(n0 + (idx >> 2)) * K + k0 + (idx & 3) * 8], &Bt[idx * 8]);
      idx = t + 256;
      gload_lds16(&A[(size_t)(m0 + (idx >> 2)) * K + k0 + (idx & 3) * 8], &At[idx * 8]);
      gload_lds16(&B[(size_t)(n0 + (idx >> 2)) * K + k0 + (idx & 3) * 8], &Bt[idx * 8]);
    }
    __syncthreads();
    bf16x8 af[4], bfr[4];
    #pragma unroll
    for (int mi = 0; mi < 4; mi++)
      af[mi] = *(const bf16x8*)&At[(wr * 64 + mi * 16 + lr) * 32 + lg * 8];
    #pragma unroll
    for (int nj = 0; nj < 4; nj++)
      bfr[nj] = *(const bf16x8*)&Bt[(wc * 64 + nj * 16 + lr) * 32 + lg * 8];
    #pragma unroll
    for (int mi = 0; mi < 4; mi++)
      #pragma unroll
      for (int nj = 0; nj < 4; nj++)
        acc[mi][nj] = __builtin_amdgcn_mfma_f32_16x16x32_bf16(af[mi], bfr[nj], acc[mi][nj], 0, 0, 0);
  }

  #pragma unroll
  for (int mi = 0; mi < 4; mi++)
    #pragma unroll
    for (int nj = 0; nj < 4; nj++){
      f32x4 v = acc[mi][nj];
      int col  = n0 + wc * 64 + nj * 16 + lr;
      int row0 = m0 + wr * 64 + mi * 16 + lg * 4;
      #pragma unroll
      for (int j = 0; j < 4; j++)
        C[(size_t)(row0 + j) * DM + col] = v[j];
    }
}

// ---------------- flash attention, swapped-QK^T 32x32 structure ----------------
// grid (NH, SEQ/128); blockIdx.y REVERSED so heaviest q-tiles dispatch first (LPT).
// 4 waves x 32 q-rows = 128 q-rows per block. KV tile = 64 keys.
// S^T = mfma(A=K, B=Q): lane ql=lane&31 holds q-col; regs hold keys
// key(r,hi) = (r&3)+8*(r>>2)+4*hi. Softmax fully in-register.
// PV: A=P (m=q, k=key) built via pack + half-swap shuffles; B=V^T from LDS.
__global__ __launch_bounds__(256) void attn2_kernel(const unsigned short* __restrict__ Qb,
                                                    const unsigned short* __restrict__ Kb,
                                                    const unsigned short* __restrict__ Vt,
                                                    unsigned short* __restrict__ AO)
{
  __shared__ unsigned short Kt[64 * 64];  // [key][d] chunk-swizzled
  __shared__ unsigned short Vs[64 * 64];  // [d][key] chunk-swizzled

  const int h = blockIdx.x;
  const int qi = (int)gridDim.y - 1 - (int)blockIdx.y;
  const int q0 = qi * 128;
  const int t = threadIdx.x, w = t >> 6, lane = t & 63;
  const int ql = lane & 31, hi = lane >> 5;
  const int qrow = q0 + w * 32 + ql;
  const int qmax = q0 + w * 32 + 31;

  // Q B-fragments: n = ql, k-elems d = ds*16 + hi*8 + j
  bf16x8 qf[4];
  #pragma unroll
  for (int ds = 0; ds < 4; ds++)
    qf[ds] = *(const bf16x8*)&Qb[(size_t)qrow * DM + h * 64 + ds * 16 + hi * 8];

  f32x16 oacc[2];
  #pragma unroll
  for (int d = 0; d < 2; d++)
    #pragma unroll
    for (int r = 0; r < 16; r++) oacc[d][r] = 0.f;
  float mrun = -INFINITY, lrun = 0.f;

  const int ktiles = (q0 + 128) >> 6;
  for (int kt = 0; kt < ktiles; kt++){
    const int k0 = kt << 6;
    __syncthreads();
    #pragma unroll
    for (int r = 0; r < 2; r++){
      int idx = r * 256 + t, row = idx >> 3, ch = idx & 7, cs = ch ^ (row & 7);
      gload_lds16(&Kb[(size_t)(k0 + row) * DM + h * 64 + cs * 8], &Kt[idx * 8]);
    }
    #pragma unroll
    for (int r = 0; r < 2; r++){
      int idx = r * 256 + t, row = idx >> 3, ch = idx & 7, cs = ch ^ (row & 7);
      gload_lds16(&Vt[(size_t)(h * 64 + row) * SEQ + k0 + cs * 8], &Vs[idx * 8]);
    }
    __syncthreads();
    if (k0 > qmax) continue;   // fully masked tile for this wave (barriers already done)

    // ---- S^T = K · Q^T ----
    float p[32];
    const bool diag = (k0 + 63 > q0 + w * 32);
    #pragma unroll
    for (int st = 0; st < 2; st++){
      f32x16 s;
      #pragma unroll
      for (int r = 0; r < 16; r++) s[r] = 0.f;
      #pragma unroll
      for (int ds = 0; ds < 4; ds++){
        int key = st * 32 + ql;
        int ch = ds * 2 + hi;
        bf16x8 kf = *(const bf16x8*)((const char*)Kt + key * 128 + ((ch ^ (key & 7)) << 4));
        s = __builtin_amdgcn_mfma_f32_32x32x16_bf16(kf, qf[ds], s, 0, 0, 0);
      }
      if (diag){
        #pragma unroll
        for (int r = 0; r < 16; r++){
          int key = k0 + st * 32 + (r & 3) + 8 * (r >> 2) + 4 * hi;
          p[st * 16 + r] = (key > qrow) ? -INFINITY : s[r];
        }
      } else {
        #pragma unroll
        for (int r = 0; r < 16; r++) p[st * 16 + r] = s[r];
      }
    }

    // ---- online softmax (in-register, defer-max) ----
    float tm = p[0];
    #pragma unroll
    for (int i = 1; i < 32; i++) tm = fmaxf(tm, p[i]);
    tm = fmaxf(tm, __shfl_xor(tm, 32));
    const bool defer = __all(tm <= mrun + 8.f) != 0;
    const float mnew = defer ? mrun : fmaxf(mrun, tm);
    float ts = 0.f;
    #pragma unroll
    for (int i = 0; i < 32; i++){
      p[i] = __builtin_amdgcn_exp2f(p[i] - mnew);
      ts += p[i];
    }
    ts += __shfl_xor(ts, 32);
    if (!defer){
      float alpha = __builtin_amdgcn_exp2f(mrun - mnew);
      mrun = mnew;
      lrun = lrun * alpha + ts;
      #pragma unroll
      for (int r = 0; r < 16; r++){
        float ar = __shfl(alpha, (r & 3) + 8 * (r >> 2) + 4 * hi);
        oacc[0][r] *= ar;
        oacc[1][r] *= ar;
      }
    } else {
      lrun += ts;
    }

    // ---- PV: A=P fragments via pack + half-swap; B=V^T from LDS ----
    #pragma unroll
    for (int ks = 0; ks < 4; ks++){
      int b = ks * 8;
      unsigned int a  = pk2(p[b + 0], p[b + 1]);
      unsigned int c  = pk2(p[b + 2], p[b + 3]);
      unsigned int bb = pk2(p[b + 4], p[b + 5]);
      unsigned int d  = pk2(p[b + 6], p[b + 7]);
      unsigned int sa = (unsigned int)__shfl_xor((int)a, 32);
      unsigned int sc = (unsigned int)__shfl_xor((int)c, 32);
      unsigned int sb = (unsigned int)__shfl_xor((int)bb, 32);
      unsigned int sd = (unsigned int)__shfl_xor((int)d, 32);
      union { u32x4 u; bf16x8 v; } pf;
      pf.u[0] = hi ? sb : a;
      pf.u[1] = hi ? sd : c;
      pf.u[2] = hi ? bb : sa;
      pf.u[3] = hi ? d  : sc;
      #pragma unroll
      for (int dcol = 0; dcol < 2; dcol++){
        int dd = dcol * 32 + ql;
        int ch = ks * 2 + hi;
        bf16x8 vf = *(const bf16x8*)((const char*)Vs + dd * 128 + ((ch ^ (dd & 7)) << 4));
        oacc[dcol] = __builtin_amdgcn_mfma_f32_32x32x16_bf16(pf.v, vf, oacc[dcol], 0, 0, 0);
      }
    }
  }

  // ---- epilogue: O /= l ----
  float rl = 1.f / lrun;
  #pragma unroll
  for (int r = 0; r < 16; r++){
    int rowloc = (r & 3) + 8 * (r >> 2) + 4 * hi;
    float rr = __shfl(rl, rowloc);
    int row = q0 + w * 32 + rowloc;
    #pragma unroll
    for (int dcol = 0; dcol < 2; dcol++)
      AO[(size_t)row * DM + h * 64 + dcol * 32 + ql] = f2bf(oacc[dcol][r] * rr);
  }
}

extern "C" void kernel_launch(void* const* d_in, const int* in_sizes, int n_in,
                              void* d_out, int out_size, void* d_ws, size_t ws_size,
                              hipStream_t stream)
{
  const float* x  = (const float*)d_in[0];
  const float* Wq = (const float*)d_in[1];
  const float* Wk = (const float*)d_in[2];
  const float* Wv = (const float*)d_in[3];
  const float* Wo = (const float*)d_in[4];

  char* ws = (char*)d_ws;
  unsigned short* xb  = (unsigned short*)ws; ws += (size_t)SEQ * DM * 2;
  unsigned short* wqb = (unsigned short*)ws; ws += (size_t)DM * DM * 2;
  unsigned short* wkb = (unsigned short*)ws; ws += (size_t)DM * DM * 2;
  unsigned short* wvb = (unsigned short*)ws; ws += (size_t)DM * DM * 2;
  unsigned short* wob = (unsigned short*)ws; ws += (size_t)DM * DM * 2;
  unsigned short* Qb  = (unsigned short*)ws; ws += (size_t)SEQ * DM * 2;
  unsigned short* Kb  = (unsigned short*)ws; ws += (size_t)SEQ * DM * 2;
  unsigned short* Vtw = (unsigned short*)ws; ws += (size_t)DM * SEQ * 2;
  unsigned short* AO  = (unsigned short*)ws; ws += (size_t)SEQ * DM * 2;
  float2* ropetab     = (float2*)ws;         ws += (size_t)SEQ * 32 * sizeof(float2);

  f2bf_kernel<<<1024, 256, 0, stream>>>(x,  xb,  SEQ * DM / 4);
  f2bf_kernel<<<512,  256, 0, stream>>>(Wq, wqb, DM * DM / 4);
  f2bf_kernel<<<512,  256, 0, stream>>>(Wk, wkb, DM * DM / 4);
  f2bf_kernel<<<512,  256, 0, stream>>>(Wv, wvb, DM * DM / 4);
  f2bf_kernel<<<512,  256, 0, stream>>>(Wo, wob, DM * DM / 4);
  rope_tab_kernel<<<SEQ * 32 / 256, 256, 0, stream>>>(ropetab);

  qkv_gemm<<<dim3(24, 32), 256, 0, stream>>>(xb, wqb, wkb, wvb, Qb, Kb, Vtw, ropetab);

  attn2_kernel<<<dim3(NH, SEQ / 128), 256, 0, stream>>>(Qb, Kb, Vtw, AO);

  gemm_out<<<dim3(8, 32), 256, 0, stream>>>(AO, wob, (float*)d_out);
}